// Round 19
// baseline (84.185 us; speedup 1.0000x reference)
//
#include <hip/hip_runtime.h>
#include <hip/hip_bf16.h>
#include <cstddef>

#define B_  8
#define S_  512
#define HID 1024
#define H_  16
#define D_  64

typedef float f32x4 __attribute__((ext_vector_type(4)));
typedef _Float16 f16x8 __attribute__((ext_vector_type(8)));
typedef short s16x8 __attribute__((ext_vector_type(8)));
typedef unsigned short u16t;

__device__ __forceinline__ u16t f2h(float v) {
    return __builtin_bit_cast(u16t, (_Float16)v);
}

// async global->LDS, 16B per lane (dest = wave-uniform base + lane*16)
__device__ __forceinline__ void gll16(const u16t* g, u16t* l) {
    __builtin_amdgcn_global_load_lds(
        (const __attribute__((address_space(1))) unsigned int*)(const void*)g,
        (__attribute__((address_space(3))) unsigned int*)(void*)l, 16, 0, 0);
}

// one fused conversion kernel: X (f32->fp16) then Wq,Wk,Wv
__global__ __launch_bounds__(256) void conv_all_kernel(
    const float* __restrict__ X,
    const float* __restrict__ Wq, const float* __restrict__ Wk,
    const float* __restrict__ Wv,
    u16t* __restrict__ Xh, u16t* __restrict__ Wh)
{
    const int nX4 = (B_ * S_ * HID) / 4;
    const int nW4 = (HID * HID) / 4;
    int i = blockIdx.x * 256 + threadIdx.x;
    const float* src;
    u16t* dst;
    int off;
    if (i < nX4)                { src = X;  dst = Xh;                         off = i; }
    else if (i < nX4 + nW4)     { src = Wq; dst = Wh;                         off = i - nX4; }
    else if (i < nX4 + 2 * nW4) { src = Wk; dst = Wh + (size_t)HID * HID;     off = i - nX4 - nW4; }
    else                        { src = Wv; dst = Wh + (size_t)2 * HID * HID; off = i - nX4 - 2 * nW4; }
    float4 x = ((const float4*)src)[off];
    ushort4 h;
    h.x = f2h(x.x);
    h.y = f2h(x.y);
    h.z = f2h(x.z);
    h.w = f2h(x.w);
    ((ushort4*)dst)[off] = h;
}

// ---------------------------------------------------------------------------
// QKV projection, pure fp16 MFMA, BK=64 double-buffered (unchanged, round 18).
// Q and V stored TRANSPOSED [B,H,D,S]; K via LDS transpose -> [B,H,S,D].
// ---------------------------------------------------------------------------
__global__ __launch_bounds__(256) void qkv_mfma_kernel(
    const u16t* __restrict__ Xhi, const u16t* __restrict__ Whi,
    const float* __restrict__ bq, const float* __restrict__ bk,
    const float* __restrict__ bv,
    u16t* __restrict__ Qth, u16t* __restrict__ Kh, u16t* __restrict__ Vth)
{
    const int which = blockIdx.z;
    const u16t* __restrict__ WhiB = Whi + (size_t)which * (HID * HID);
    const float* __restrict__ bias = (which == 0) ? bq : (which == 1) ? bk : bv;

    __shared__ __align__(16) u16t SM[2 * 16384];

    const int tid  = threadIdx.x;
    const int lane = tid & 63;
    const int wv_  = tid >> 6;
    const int wr   = wv_ >> 1;
    const int wc   = wv_ & 1;
    const int m0   = blockIdx.y * 128;
    const int n0   = blockIdx.x * 128;

    f32x4 acc[4][4];
    #pragma unroll
    for (int mi = 0; mi < 4; ++mi)
        #pragma unroll
        for (int ni = 0; ni < 4; ++ni)
            #pragma unroll
            for (int e = 0; e < 4; ++e) acc[mi][ni][e] = 0.0f;

    const int rowB0 = wv_ * 32 + (lane >> 3);
    const int ch    = (lane & 7) ^ (rowB0 & 7);
    const size_t aof = (size_t)(m0 + rowB0) * HID + ch * 8;
    const size_t bof = (size_t)(n0 + rowB0) * HID + ch * 8;
    const int ldsA = (wv_ * 32) * 64;

    const int colL = lane & 15;
    const int kg   = lane >> 4;
    const int sx   = colL & 7;
    const int arow = (wr * 64 + colL) * 64;
    const int brow = (wc * 64 + colL) * 64;

    #pragma unroll
    for (int s = 0; s < 4; ++s) {
        gll16(&Xhi [aof + (size_t)(s * 8) * HID], SM + ldsA + s * 512);
        gll16(&WhiB[bof + (size_t)(s * 8) * HID], SM + 8192 + ldsA + s * 512);
    }
    __syncthreads();

    for (int k0 = 0; k0 < HID; k0 += 64) {
        const int cur = (k0 >> 6) & 1;
        u16t* const bufc = SM + cur * 16384;
        if (k0 + 64 < HID) {
            u16t* const bufn = SM + (cur ^ 1) * 16384;
            #pragma unroll
            for (int s = 0; s < 4; ++s) {
                gll16(&Xhi [aof + k0 + 64 + (size_t)(s * 8) * HID], bufn + ldsA + s * 512);
                gll16(&WhiB[bof + k0 + 64 + (size_t)(s * 8) * HID], bufn + 8192 + ldsA + s * 512);
            }
        }

        #pragma unroll
        for (int ks = 0; ks < 2; ++ks) {
            const int so = ((ks * 4 + kg) ^ sx) * 8;
            f16x8 a_[4], b_[4];
            #pragma unroll
            for (int mi = 0; mi < 4; ++mi)
                a_[mi] = *(const f16x8*)&bufc[arow + mi * 1024 + so];
            #pragma unroll
            for (int ni = 0; ni < 4; ++ni)
                b_[ni] = *(const f16x8*)&bufc[8192 + brow + ni * 1024 + so];
            #pragma unroll
            for (int mi = 0; mi < 4; ++mi)
                #pragma unroll
                for (int ni = 0; ni < 4; ++ni)
                    acc[mi][ni] = __builtin_amdgcn_mfma_f32_16x16x32_f16(
                        a_[mi], b_[ni], acc[mi][ni], 0, 0, 0);
        }
        __syncthreads();
    }

    if (which != 1) {
        u16t* __restrict__ O = (which == 0) ? Qth : Vth;
        #pragma unroll
        for (int mi = 0; mi < 4; ++mi) {
            #pragma unroll
            for (int ni = 0; ni < 4; ++ni) {
                const int n    = n0 + wc * 64 + ni * 16 + colL;
                const int mrow = m0 + wr * 64 + mi * 16 + kg * 4;
                const float bn = bias[n];
                const int bb = mrow >> 9;
                const int ss = mrow & (S_ - 1);
                const int hh = n >> 6;
                const int dd = n & (D_ - 1);
                ushort4 vh;
                vh.x = f2h(acc[mi][ni][0] + bn);
                vh.y = f2h(acc[mi][ni][1] + bn);
                vh.z = f2h(acc[mi][ni][2] + bn);
                vh.w = f2h(acc[mi][ni][3] + bn);
                *(ushort4*)&O[(((size_t)bb * H_ + hh) * D_ + dd) * S_ + ss] = vh;
            }
        }
    } else {
        float* LF = (float*)SM;
        float bn4[4];
        #pragma unroll
        for (int ni = 0; ni < 4; ++ni) bn4[ni] = bias[n0 + wc * 64 + ni * 16 + colL];

        const int er  = tid >> 3;
        const int ecc = (tid & 7) * 16;
        const int ehh = (n0 + ecc) >> 6;
        const int edd = ecc & 63;
        const int mrowE = m0 + (er >> 4) * 64 + (er & 15);

        #pragma unroll
        for (int mi = 0; mi < 4; ++mi) {
            __syncthreads();
            #pragma unroll
            for (int ni = 0; ni < 4; ++ni)
                #pragma unroll
                for (int j = 0; j < 4; ++j)
                    LF[(wr * 16 + kg * 4 + j) * 130 + wc * 64 + ni * 16 + colL] =
                        acc[mi][ni][j] + bn4[ni];
            __syncthreads();

            const int mrow = mrowE + mi * 16;
            const int bb = mrow >> 9;
            const int ss = mrow & (S_ - 1);
            __align__(16) u16t hv[16];
            #pragma unroll
            for (int u = 0; u < 16; u += 4) {
                float4 v = *(const float4*)&LF[er * 130 + ecc + u];
                hv[u + 0] = f2h(v.x);
                hv[u + 1] = f2h(v.y);
                hv[u + 2] = f2h(v.z);
                hv[u + 3] = f2h(v.w);
            }
            const size_t off = (((size_t)bb * H_ + ehh) * S_ + ss) * D_ + edd;
            *(s16x8*)&Kh[off]     = *(const s16x8*)&hv[0];
            *(s16x8*)&Kh[off + 8] = *(const s16x8*)&hv[8];
        }
    }
}

// ---------------------------------------------------------------------------
// MFMA flash attention v9 = v8 + TWO k-tiles per loop iteration:
// 4 iterations x 128 k; barriers halve (8 -> 4); prefetch distance doubles
// (tiles t+2,t+3 issued while t,t+1 compute).  LDS 80KB: 2 halves x
// (K0|V0|K1|V1, 32KB) + per-wave P (16KB).  2 blocks/CU.
// Same tile order and sums as v8 -> absmax unchanged.
// ---------------------------------------------------------------------------
__global__ __launch_bounds__(512) void attn_mfma_kernel(
    const u16t* __restrict__ Qtg, const u16t* __restrict__ Khg,
    const u16t* __restrict__ Vhg,
    const int*  __restrict__ ge,  const float* __restrict__ mask,
    const float* __restrict__ dpk, const float* __restrict__ dpv,
    float* __restrict__ out)
{
    __shared__ __align__(16) u16t SM[40960];   // 80 KB

    const int tid  = threadIdx.x;
    const int lane = tid & 63;
    const int wq   = tid >> 6;
    const int c    = lane & 15;
    const int g    = lane >> 4;
    const int sx   = c & 7;
    const int bid  = blockIdx.x;
    const int bh   = bid >> 2;
    const int q0   = (bid & 3) * 128;
    const int b    = bh >> 4;
    const int h    = bh & (H_ - 1);

    u16t* Pw = SM + 32768 + wq * 1024;

    // ---- Q fragments from Qt[B,H,D,S]: 16 strided scalar loads ----
    const int qrow = q0 + wq * 16 + c;
    const u16t* qtb = Qtg + (size_t)bh * D_ * S_ + qrow;
    f16x8 qA, qB;
    #pragma unroll
    for (int i = 0; i < 8; ++i) {
        qA[i] = __builtin_bit_cast(_Float16, qtb[(size_t)(g * 8 + i) * S_]);
        qB[i] = __builtin_bit_cast(_Float16, qtb[(size_t)((g + 4) * 8 + i) * S_]);
    }

    float tq1, tq2;
    {
        float a1 = 0.f, a2 = 0.f;
        #pragma unroll
        for (int i = 0; i < 8; ++i) {
            const float x0 = (float)qA[i];
            const float x1 = (float)qB[i];
            a1 = fmaf(x0, dpk[D_ + g * 8 + i], a1);
            a1 = fmaf(x1, dpk[D_ + (g + 4) * 8 + i], a1);
            a2 = fmaf(x0, dpk[2 * D_ + g * 8 + i], a2);
            a2 = fmaf(x1, dpk[2 * D_ + (g + 4) * 8 + i], a2);
        }
        a1 += __shfl_xor(a1, 16); a1 += __shfl_xor(a1, 32);
        a2 += __shfl_xor(a2, 16); a2 += __shfl_xor(a2, 32);
        tq1 = a1; tq2 = a2;
    }

    const int r_   = tid >> 3;
    const int s_   = tid & 7;
    const int ldso = r_ * 64 + ((s_ ^ (r_ & 7)) << 3);
    const u16t* kgp = &Khg[((size_t)bh * S_ + r_) * D_ + s_ * 8];
    const u16t* vgp = &Vhg[((size_t)bh * D_ + r_) * S_ + s_ * 8];

    // prologue: tiles 0 and 1 into regs
    s16x8 krS0 = *(const s16x8*)kgp;
    s16x8 vrS0 = *(const s16x8*)vgp;
    s16x8 krS1 = *(const s16x8*)(kgp + (size_t)64 * D_);
    s16x8 vrS1 = *(const s16x8*)(vgp + 64);

    const size_t geoff = ((size_t)b * S_ + qrow) * S_;
    const float* mrow = &mask[(size_t)b * S_];

    float lrun = 0.f, w1 = 0.f, w2 = 0.f;   // per-lane partials, deferred reduce
    f32x4 ctx4[4];
    #pragma unroll
    for (int mi = 0; mi < 4; ++mi)
        #pragma unroll
        for (int e = 0; e < 4; ++e) ctx4[mi][e] = 0.f;

    for (int it = 0; it < 4; ++it) {
        const int k0 = it * 128;
        u16t* const half_ = SM + ((it & 1) << 14);   // 0 / 16384 u16

        // commit both staged tiles into this half
        *(s16x8*)&half_[ldso]         = krS0;   // K tile A
        *(s16x8*)&half_[4096 + ldso]  = vrS0;   // V tile A
        *(s16x8*)&half_[8192 + ldso]  = krS1;   // K tile B
        *(s16x8*)&half_[12288 + ldso] = vrS1;   // V tile B

        // prefetch the next pair (T14: hide under this iteration's compute)
        if (it < 3) {
            krS0 = *(const s16x8*)(kgp + (size_t)(k0 + 128) * D_);
            vrS0 = *(const s16x8*)(vgp + (k0 + 128));
            krS1 = *(const s16x8*)(kgp + (size_t)(k0 + 192) * D_);
            vrS1 = *(const s16x8*)(vgp + (k0 + 192));
        }

        __syncthreads();   // both tiles of this half visible

        #pragma unroll
        for (int sub = 0; sub < 2; ++sub) {
            u16t* const Kb = half_ + sub * 8192;
            u16t* const Vb = Kb + 4096;
            const int ks0 = k0 + sub * 64;

            int4   gc4[4];
            float4 mk4[4];
            #pragma unroll
            for (int mi = 0; mi < 4; ++mi) {
                gc4[mi] = *(const int4*)&ge[geoff + ks0 + mi * 16 + g * 4];
                mk4[mi] = *(const float4*)&mrow[ks0 + mi * 16 + g * 4];
            }

            f32x4 s4[4];
            #pragma unroll
            for (int mi = 0; mi < 4; ++mi)
                #pragma unroll
                for (int e = 0; e < 4; ++e) s4[mi][e] = 0.f;

            __builtin_amdgcn_s_setprio(1);
            #pragma unroll
            for (int ks = 0; ks < 2; ++ks) {
                const int so = ((g + 4 * ks) ^ sx) << 3;
                const f16x8 qh_ = ks ? qB : qA;
                #pragma unroll
                for (int mi = 0; mi < 4; ++mi) {
                    const f16x8 kh_ = *(const f16x8*)&Kb[(mi * 16 + c) * 64 + so];
                    s4[mi] = __builtin_amdgcn_mfma_f32_16x16x32_f16(kh_, qh_, s4[mi], 0, 0, 0);
                }
            }
            __builtin_amdgcn_s_setprio(0);

            // fused score -> exp(s-8) -> per-lane partial sums
            float sv[4][4];
            #pragma unroll
            for (int mi = 0; mi < 4; ++mi) {
                const int   gg[4] = {gc4[mi].x, gc4[mi].y, gc4[mi].z, gc4[mi].w};
                const float mm[4] = {mk4[mi].x, mk4[mi].y, mk4[mi].z, mk4[mi].w};
                #pragma unroll
                for (int j = 0; j < 4; ++j) {
                    const float t = (gg[j] == 1) ? tq1 : (gg[j] == 2) ? tq2 : 0.f;
                    const float e = __expf(fmaf(s4[mi][j], 0.125f, t + mm[j] - 8.0f));
                    sv[mi][j] = e;
                    lrun += e;
                    w1 += (gg[j] == 1) ? e : 0.f;
                    w2 += (gg[j] == 2) ? e : 0.f;
                }
            }

            #pragma unroll
            for (int mi = 0; mi < 4; ++mi) {
                ushort4 ph;
                ph.x = f2h(sv[mi][0]);
                ph.y = f2h(sv[mi][1]);
                ph.z = f2h(sv[mi][2]);
                ph.w = f2h(sv[mi][3]);
                const int slotp = (2 * mi + (g >> 1)) ^ sx;
                *(ushort4*)&Pw[c * 64 + slotp * 8 + (g & 1) * 4] = ph;
            }

            __builtin_amdgcn_s_setprio(1);
            #pragma unroll
            for (int ks = 0; ks < 2; ++ks) {
                const int so = ((g + 4 * ks) ^ sx) << 3;
                const f16x8 ph_ = *(const f16x8*)&Pw[c * 64 + so];
                #pragma unroll
                for (int mi = 0; mi < 4; ++mi) {
                    const f16x8 vh_ = *(const f16x8*)&Vb[(mi * 16 + c) * 64 + so];
                    ctx4[mi] = __builtin_amdgcn_mfma_f32_16x16x32_f16(vh_, ph_, ctx4[mi], 0, 0, 0);
                }
            }
            __builtin_amdgcn_s_setprio(0);
        }
    }

    // deferred cross-lane reduction (once)
    lrun += __shfl_xor(lrun, 16); lrun += __shfl_xor(lrun, 32);
    w1   += __shfl_xor(w1, 16);   w1   += __shfl_xor(w1, 32);
    w2   += __shfl_xor(w2, 16);   w2   += __shfl_xor(w2, 32);

    __syncthreads();
    const float inv = 1.0f / lrun;
    float* tb = (float*)SM + wq * 1088;
    #pragma unroll
    for (int mi = 0; mi < 4; ++mi) {
        const float4 dk1 = *(const float4*)&dpv[D_ + mi * 16 + g * 4];
        const float4 dk2 = *(const float4*)&dpv[2 * D_ + mi * 16 + g * 4];
        const float a1[4] = {dk1.x, dk1.y, dk1.z, dk1.w};
        const float a2[4] = {dk2.x, dk2.y, dk2.z, dk2.w};
        #pragma unroll
        for (int j = 0; j < 4; ++j) {
            const float val = (ctx4[mi][j] + w1 * a1[j] + w2 * a2[j]) * inv;
            tb[(mi * 16 + g * 4 + j) * 17 + c] = val;
        }
    }
    __syncthreads();
    #pragma unroll
    for (int qq = 0; qq < 16; ++qq)
        out[((size_t)b * S_ + q0 + wq * 16 + qq) * (H_ * D_) + h * D_ + lane] =
            tb[lane * 17 + qq];
}

extern "C" void kernel_launch(void* const* d_in, const int* in_sizes, int n_in,
                              void* d_out, int out_size, void* d_ws, size_t ws_size,
                              hipStream_t stream)
{
    const float* hs   = (const float*)d_in[0];
    const float* mask = (const float*)d_in[1];
    const int*   ge   = (const int*)d_in[2];
    const float* Wq   = (const float*)d_in[3];
    const float* bq   = (const float*)d_in[4];
    const float* Wk   = (const float*)d_in[5];
    const float* bk   = (const float*)d_in[6];
    const float* Wv   = (const float*)d_in[7];
    const float* bv   = (const float*)d_in[8];
    const float* dpk  = (const float*)d_in[9];
    const float* dpv  = (const float*)d_in[10];
    float* out = (float*)d_out;

    const size_t per = (size_t)B_ * H_ * S_ * D_;   // 4,194,304
    const size_t nX  = (size_t)B_ * S_ * HID;       // 4,194,304
    const size_t nW  = (size_t)HID * HID;           // 1,048,576

    u16t* base = (u16t*)d_ws;
    u16t* Qth = base;
    u16t* Kh  = Qth + per;
    u16t* Vth = Kh  + per;
    u16t* Xhi = Vth + per;
    u16t* Whi = Xhi + nX;

    const int nConv = (int)((nX + 3 * nW) / 4);
    conv_all_kernel<<<nConv / 256, 256, 0, stream>>>(hs, Wq, Wk, Wv, Xhi, Whi);

    dim3 gridG(HID / 128, (B_ * S_) / 128, 3);
    qkv_mfma_kernel<<<gridG, dim3(256), 0, stream>>>(
        Xhi, Whi, bq, bk, bv, Qth, Kh, Vth);

    dim3 gridB(B_ * H_ * (S_ / 128));
    attn_mfma_kernel<<<gridB, dim3(512), 0, stream>>>(
        Qth, Kh, Vth, ge, mask, dpk, dpv, out);
}

// Round 20
// 74.336 us; speedup vs baseline: 1.1325x; 1.1325x over previous
//
#include <hip/hip_runtime.h>
#include <hip/hip_bf16.h>
#include <cstddef>

#define B_  8
#define S_  512
#define HID 1024
#define H_  16
#define D_  64

typedef float f32x4 __attribute__((ext_vector_type(4)));
typedef _Float16 f16x8 __attribute__((ext_vector_type(8)));
typedef short s16x8 __attribute__((ext_vector_type(8)));
typedef unsigned short u16t;

__device__ __forceinline__ u16t f2h(float v) {
    return __builtin_bit_cast(u16t, (_Float16)v);
}

// async global->LDS, 16B per lane (dest = wave-uniform base + lane*16)
__device__ __forceinline__ void gll16(const u16t* g, u16t* l) {
    __builtin_amdgcn_global_load_lds(
        (const __attribute__((address_space(1))) unsigned int*)(const void*)g,
        (__attribute__((address_space(3))) unsigned int*)(void*)l, 16, 0, 0);
}

// one fused conversion kernel: X (f32->fp16) then Wq,Wk,Wv
__global__ __launch_bounds__(256) void conv_all_kernel(
    const float* __restrict__ X,
    const float* __restrict__ Wq, const float* __restrict__ Wk,
    const float* __restrict__ Wv,
    u16t* __restrict__ Xh, u16t* __restrict__ Wh)
{
    const int nX4 = (B_ * S_ * HID) / 4;
    const int nW4 = (HID * HID) / 4;
    int i = blockIdx.x * 256 + threadIdx.x;
    const float* src;
    u16t* dst;
    int off;
    if (i < nX4)                { src = X;  dst = Xh;                         off = i; }
    else if (i < nX4 + nW4)     { src = Wq; dst = Wh;                         off = i - nX4; }
    else if (i < nX4 + 2 * nW4) { src = Wk; dst = Wh + (size_t)HID * HID;     off = i - nX4 - nW4; }
    else                        { src = Wv; dst = Wh + (size_t)2 * HID * HID; off = i - nX4 - 2 * nW4; }
    float4 x = ((const float4*)src)[off];
    ushort4 h;
    h.x = f2h(x.x);
    h.y = f2h(x.y);
    h.z = f2h(x.z);
    h.w = f2h(x.w);
    ((ushort4*)dst)[off] = h;
}

// ---------------------------------------------------------------------------
// QKV projection, pure fp16 MFMA, BK=64 double-buffered (round-18, best).
// Q and V stored TRANSPOSED [B,H,D,S]; K via LDS transpose -> [B,H,S,D].
// ---------------------------------------------------------------------------
__global__ __launch_bounds__(256) void qkv_mfma_kernel(
    const u16t* __restrict__ Xhi, const u16t* __restrict__ Whi,
    const float* __restrict__ bq, const float* __restrict__ bk,
    const float* __restrict__ bv,
    u16t* __restrict__ Qth, u16t* __restrict__ Kh, u16t* __restrict__ Vth)
{
    const int which = blockIdx.z;
    const u16t* __restrict__ WhiB = Whi + (size_t)which * (HID * HID);
    const float* __restrict__ bias = (which == 0) ? bq : (which == 1) ? bk : bv;

    __shared__ __align__(16) u16t SM[2 * 16384];

    const int tid  = threadIdx.x;
    const int lane = tid & 63;
    const int wv_  = tid >> 6;
    const int wr   = wv_ >> 1;
    const int wc   = wv_ & 1;
    const int m0   = blockIdx.y * 128;
    const int n0   = blockIdx.x * 128;

    f32x4 acc[4][4];
    #pragma unroll
    for (int mi = 0; mi < 4; ++mi)
        #pragma unroll
        for (int ni = 0; ni < 4; ++ni)
            #pragma unroll
            for (int e = 0; e < 4; ++e) acc[mi][ni][e] = 0.0f;

    const int rowB0 = wv_ * 32 + (lane >> 3);
    const int ch    = (lane & 7) ^ (rowB0 & 7);
    const size_t aof = (size_t)(m0 + rowB0) * HID + ch * 8;
    const size_t bof = (size_t)(n0 + rowB0) * HID + ch * 8;
    const int ldsA = (wv_ * 32) * 64;

    const int colL = lane & 15;
    const int kg   = lane >> 4;
    const int sx   = colL & 7;
    const int arow = (wr * 64 + colL) * 64;
    const int brow = (wc * 64 + colL) * 64;

    #pragma unroll
    for (int s = 0; s < 4; ++s) {
        gll16(&Xhi [aof + (size_t)(s * 8) * HID], SM + ldsA + s * 512);
        gll16(&WhiB[bof + (size_t)(s * 8) * HID], SM + 8192 + ldsA + s * 512);
    }
    __syncthreads();

    for (int k0 = 0; k0 < HID; k0 += 64) {
        const int cur = (k0 >> 6) & 1;
        u16t* const bufc = SM + cur * 16384;
        if (k0 + 64 < HID) {
            u16t* const bufn = SM + (cur ^ 1) * 16384;
            #pragma unroll
            for (int s = 0; s < 4; ++s) {
                gll16(&Xhi [aof + k0 + 64 + (size_t)(s * 8) * HID], bufn + ldsA + s * 512);
                gll16(&WhiB[bof + k0 + 64 + (size_t)(s * 8) * HID], bufn + 8192 + ldsA + s * 512);
            }
        }

        #pragma unroll
        for (int ks = 0; ks < 2; ++ks) {
            const int so = ((ks * 4 + kg) ^ sx) * 8;
            f16x8 a_[4], b_[4];
            #pragma unroll
            for (int mi = 0; mi < 4; ++mi)
                a_[mi] = *(const f16x8*)&bufc[arow + mi * 1024 + so];
            #pragma unroll
            for (int ni = 0; ni < 4; ++ni)
                b_[ni] = *(const f16x8*)&bufc[8192 + brow + ni * 1024 + so];
            #pragma unroll
            for (int mi = 0; mi < 4; ++mi)
                #pragma unroll
                for (int ni = 0; ni < 4; ++ni)
                    acc[mi][ni] = __builtin_amdgcn_mfma_f32_16x16x32_f16(
                        a_[mi], b_[ni], acc[mi][ni], 0, 0, 0);
        }
        __syncthreads();
    }

    if (which != 1) {
        u16t* __restrict__ O = (which == 0) ? Qth : Vth;
        #pragma unroll
        for (int mi = 0; mi < 4; ++mi) {
            #pragma unroll
            for (int ni = 0; ni < 4; ++ni) {
                const int n    = n0 + wc * 64 + ni * 16 + colL;
                const int mrow = m0 + wr * 64 + mi * 16 + kg * 4;
                const float bn = bias[n];
                const int bb = mrow >> 9;
                const int ss = mrow & (S_ - 1);
                const int hh = n >> 6;
                const int dd = n & (D_ - 1);
                ushort4 vh;
                vh.x = f2h(acc[mi][ni][0] + bn);
                vh.y = f2h(acc[mi][ni][1] + bn);
                vh.z = f2h(acc[mi][ni][2] + bn);
                vh.w = f2h(acc[mi][ni][3] + bn);
                *(ushort4*)&O[(((size_t)bb * H_ + hh) * D_ + dd) * S_ + ss] = vh;
            }
        }
    } else {
        float* LF = (float*)SM;
        float bn4[4];
        #pragma unroll
        for (int ni = 0; ni < 4; ++ni) bn4[ni] = bias[n0 + wc * 64 + ni * 16 + colL];

        const int er  = tid >> 3;
        const int ecc = (tid & 7) * 16;
        const int ehh = (n0 + ecc) >> 6;
        const int edd = ecc & 63;
        const int mrowE = m0 + (er >> 4) * 64 + (er & 15);

        #pragma unroll
        for (int mi = 0; mi < 4; ++mi) {
            __syncthreads();
            #pragma unroll
            for (int ni = 0; ni < 4; ++ni)
                #pragma unroll
                for (int j = 0; j < 4; ++j)
                    LF[(wr * 16 + kg * 4 + j) * 130 + wc * 64 + ni * 16 + colL] =
                        acc[mi][ni][j] + bn4[ni];
            __syncthreads();

            const int mrow = mrowE + mi * 16;
            const int bb = mrow >> 9;
            const int ss = mrow & (S_ - 1);
            __align__(16) u16t hv[16];
            #pragma unroll
            for (int u = 0; u < 16; u += 4) {
                float4 v = *(const float4*)&LF[er * 130 + ecc + u];
                hv[u + 0] = f2h(v.x);
                hv[u + 1] = f2h(v.y);
                hv[u + 2] = f2h(v.z);
                hv[u + 3] = f2h(v.w);
            }
            const size_t off = (((size_t)bb * H_ + ehh) * S_ + ss) * D_ + edd;
            *(s16x8*)&Kh[off]     = *(const s16x8*)&hv[0];
            *(s16x8*)&Kh[off + 8] = *(const s16x8*)&hv[8];
        }
    }
}

// ---------------------------------------------------------------------------
// MFMA flash attention v8 (round-18, best measured): static-shift softmax
// p=exp(s-8), deferred softmax-sum reduction, Q from Qt via strided loads,
// K/V dbuf + 1 barrier/tile (48 KB LDS), T14 early loads, setprio, swizzles.
// ---------------------------------------------------------------------------
__global__ __launch_bounds__(512) void attn_mfma_kernel(
    const u16t* __restrict__ Qtg, const u16t* __restrict__ Khg,
    const u16t* __restrict__ Vhg,
    const int*  __restrict__ ge,  const float* __restrict__ mask,
    const float* __restrict__ dpk, const float* __restrict__ dpv,
    float* __restrict__ out)
{
    __shared__ __align__(16) u16t SM[24576];   // 48 KB

    const int tid  = threadIdx.x;
    const int lane = tid & 63;
    const int wq   = tid >> 6;
    const int c    = lane & 15;
    const int g    = lane >> 4;
    const int sx   = c & 7;
    const int bid  = blockIdx.x;
    const int bh   = bid >> 2;
    const int q0   = (bid & 3) * 128;
    const int b    = bh >> 4;
    const int h    = bh & (H_ - 1);

    u16t* Pw = SM + 16384 + wq * 1024;

    const int qrow = q0 + wq * 16 + c;
    const u16t* qtb = Qtg + (size_t)bh * D_ * S_ + qrow;
    f16x8 qA, qB;
    #pragma unroll
    for (int i = 0; i < 8; ++i) {
        qA[i] = __builtin_bit_cast(_Float16, qtb[(size_t)(g * 8 + i) * S_]);
        qB[i] = __builtin_bit_cast(_Float16, qtb[(size_t)((g + 4) * 8 + i) * S_]);
    }

    float tq1, tq2;
    {
        float a1 = 0.f, a2 = 0.f;
        #pragma unroll
        for (int i = 0; i < 8; ++i) {
            const float x0 = (float)qA[i];
            const float x1 = (float)qB[i];
            a1 = fmaf(x0, dpk[D_ + g * 8 + i], a1);
            a1 = fmaf(x1, dpk[D_ + (g + 4) * 8 + i], a1);
            a2 = fmaf(x0, dpk[2 * D_ + g * 8 + i], a2);
            a2 = fmaf(x1, dpk[2 * D_ + (g + 4) * 8 + i], a2);
        }
        a1 += __shfl_xor(a1, 16); a1 += __shfl_xor(a1, 32);
        a2 += __shfl_xor(a2, 16); a2 += __shfl_xor(a2, 32);
        tq1 = a1; tq2 = a2;
    }

    const int r_   = tid >> 3;
    const int s_   = tid & 7;
    const int ldso = r_ * 64 + ((s_ ^ (r_ & 7)) << 3);
    const u16t* kgp = &Khg[((size_t)bh * S_ + r_) * D_ + s_ * 8];
    const u16t* vgp = &Vhg[((size_t)bh * D_ + r_) * S_ + s_ * 8];

    s16x8 krS = *(const s16x8*)kgp;
    s16x8 vrS = *(const s16x8*)vgp;

    const size_t geoff = ((size_t)b * S_ + qrow) * S_;
    const float* mrow = &mask[(size_t)b * S_];

    float lrun = 0.f, w1 = 0.f, w2 = 0.f;
    f32x4 ctx4[4];
    #pragma unroll
    for (int mi = 0; mi < 4; ++mi)
        #pragma unroll
        for (int e = 0; e < 4; ++e) ctx4[mi][e] = 0.f;

    for (int kt = 0; kt < S_ / 64; ++kt) {
        const int k0 = kt * 64;
        const int bufo = (kt & 1) << 13;
        u16t* const Kb = SM + bufo;
        u16t* const Vb = SM + bufo + 4096;

        *(s16x8*)&Kb[ldso] = krS;
        *(s16x8*)&Vb[ldso] = vrS;

        if (kt < S_ / 64 - 1) {
            krS = *(const s16x8*)(kgp + (size_t)(k0 + 64) * D_);
            vrS = *(const s16x8*)(vgp + (k0 + 64));
        }
        int4   gc4[4];
        float4 mk4[4];
        #pragma unroll
        for (int mi = 0; mi < 4; ++mi) {
            gc4[mi] = *(const int4*)&ge[geoff + k0 + mi * 16 + g * 4];
            mk4[mi] = *(const float4*)&mrow[k0 + mi * 16 + g * 4];
        }

        __syncthreads();

        f32x4 s4[4];
        #pragma unroll
        for (int mi = 0; mi < 4; ++mi)
            #pragma unroll
            for (int e = 0; e < 4; ++e) s4[mi][e] = 0.f;

        __builtin_amdgcn_s_setprio(1);
        #pragma unroll
        for (int ks = 0; ks < 2; ++ks) {
            const int so = ((g + 4 * ks) ^ sx) << 3;
            const f16x8 qh_ = ks ? qB : qA;
            #pragma unroll
            for (int mi = 0; mi < 4; ++mi) {
                const f16x8 kh_ = *(const f16x8*)&Kb[(mi * 16 + c) * 64 + so];
                s4[mi] = __builtin_amdgcn_mfma_f32_16x16x32_f16(kh_, qh_, s4[mi], 0, 0, 0);
            }
        }
        __builtin_amdgcn_s_setprio(0);

        float sv[4][4];
        #pragma unroll
        for (int mi = 0; mi < 4; ++mi) {
            const int   gg[4] = {gc4[mi].x, gc4[mi].y, gc4[mi].z, gc4[mi].w};
            const float mm[4] = {mk4[mi].x, mk4[mi].y, mk4[mi].z, mk4[mi].w};
            #pragma unroll
            for (int j = 0; j < 4; ++j) {
                const float t = (gg[j] == 1) ? tq1 : (gg[j] == 2) ? tq2 : 0.f;
                const float e = __expf(fmaf(s4[mi][j], 0.125f, t + mm[j] - 8.0f));
                sv[mi][j] = e;
                lrun += e;
                w1 += (gg[j] == 1) ? e : 0.f;
                w2 += (gg[j] == 2) ? e : 0.f;
            }
        }

        #pragma unroll
        for (int mi = 0; mi < 4; ++mi) {
            ushort4 ph;
            ph.x = f2h(sv[mi][0]);
            ph.y = f2h(sv[mi][1]);
            ph.z = f2h(sv[mi][2]);
            ph.w = f2h(sv[mi][3]);
            const int slotp = (2 * mi + (g >> 1)) ^ sx;
            *(ushort4*)&Pw[c * 64 + slotp * 8 + (g & 1) * 4] = ph;
        }

        __builtin_amdgcn_s_setprio(1);
        #pragma unroll
        for (int ks = 0; ks < 2; ++ks) {
            const int so = ((g + 4 * ks) ^ sx) << 3;
            const f16x8 ph_ = *(const f16x8*)&Pw[c * 64 + so];
            #pragma unroll
            for (int mi = 0; mi < 4; ++mi) {
                const f16x8 vh_ = *(const f16x8*)&Vb[(mi * 16 + c) * 64 + so];
                ctx4[mi] = __builtin_amdgcn_mfma_f32_16x16x32_f16(vh_, ph_, ctx4[mi], 0, 0, 0);
            }
        }
        __builtin_amdgcn_s_setprio(0);
    }

    lrun += __shfl_xor(lrun, 16); lrun += __shfl_xor(lrun, 32);
    w1   += __shfl_xor(w1, 16);   w1   += __shfl_xor(w1, 32);
    w2   += __shfl_xor(w2, 16);   w2   += __shfl_xor(w2, 32);

    __syncthreads();
    const float inv = 1.0f / lrun;
    float* tb = (float*)SM + wq * 1088;
    #pragma unroll
    for (int mi = 0; mi < 4; ++mi) {
        const float4 dk1 = *(const float4*)&dpv[D_ + mi * 16 + g * 4];
        const float4 dk2 = *(const float4*)&dpv[2 * D_ + mi * 16 + g * 4];
        const float a1[4] = {dk1.x, dk1.y, dk1.z, dk1.w};
        const float a2[4] = {dk2.x, dk2.y, dk2.z, dk2.w};
        #pragma unroll
        for (int j = 0; j < 4; ++j) {
            const float val = (ctx4[mi][j] + w1 * a1[j] + w2 * a2[j]) * inv;
            tb[(mi * 16 + g * 4 + j) * 17 + c] = val;
        }
    }
    __syncthreads();
    #pragma unroll
    for (int qq = 0; qq < 16; ++qq)
        out[((size_t)b * S_ + q0 + wq * 16 + qq) * (H_ * D_) + h * D_ + lane] =
            tb[lane * 17 + qq];
}

extern "C" void kernel_launch(void* const* d_in, const int* in_sizes, int n_in,
                              void* d_out, int out_size, void* d_ws, size_t ws_size,
                              hipStream_t stream)
{
    const float* hs   = (const float*)d_in[0];
    const float* mask = (const float*)d_in[1];
    const int*   ge   = (const int*)d_in[2];
    const float* Wq   = (const float*)d_in[3];
    const float* bq   = (const float*)d_in[4];
    const float* Wk   = (const float*)d_in[5];
    const float* bk   = (const float*)d_in[6];
    const float* Wv   = (const float*)d_in[7];
    const float* bv   = (const float*)d_in[8];
    const float* dpk  = (const float*)d_in[9];
    const float* dpv  = (const float*)d_in[10];
    float* out = (float*)d_out;

    const size_t per = (size_t)B_ * H_ * S_ * D_;   // 4,194,304
    const size_t nX  = (size_t)B_ * S_ * HID;       // 4,194,304
    const size_t nW  = (size_t)HID * HID;           // 1,048,576

    u16t* base = (u16t*)d_ws;
    u16t* Qth = base;
    u16t* Kh  = Qth + per;
    u16t* Vth = Kh  + per;
    u16t* Xhi = Vth + per;
    u16t* Whi = Xhi + nX;

    const int nConv = (int)((nX + 3 * nW) / 4);
    conv_all_kernel<<<nConv / 256, 256, 0, stream>>>(hs, Wq, Wk, Wv, Xhi, Whi);

    dim3 gridG(HID / 128, (B_ * S_) / 128, 3);
    qkv_mfma_kernel<<<gridG, dim3(256), 0, stream>>>(
        Xhi, Whi, bq, bk, bv, Qth, Kh, Vth);

    dim3 gridB(B_ * H_ * (S_ / 128));
    attn_mfma_kernel<<<gridB, dim3(512), 0, stream>>>(
        Qth, Kh, Vth, ge, mask, dpk, dpv, out);
}